// Round 8
// baseline (326.031 us; speedup 1.0000x reference)
//
#include <hip/hip_runtime.h>
#include <hip/hip_cooperative_groups.h>

namespace cg = cooperative_groups;

#define NUM_EDGE_TYPES 38
#define NUM_NODE_TYPES 4
#define HIDDEN 64
#define TABLE_SIZE (NUM_EDGE_TYPES * NUM_NODE_TYPES * NUM_NODE_TYPES)  // 608
#define SRC_BITS 17
#define SRC_MASK ((1 << SRC_BITS) - 1)   // N_NODES = 100000 < 131072
#define BSHIFT 8                          // 256 dst nodes per bucket
#define BNODES 256
#define MAXB 512                          // supports N up to 131072
#define CHUNK 4096                        // edges per partition block
#define PB 512                            // partition block size
#define HB 1024                           // fallback sort/hop block size
#define MB 512                            // mega-kernel block size
#define CAPC 6144                         // max bucket capacity (LDS sort)
// pack layout: [31]=0 | et[30:25] | dstLow[24:17] | src[16:0]

__device__ __forceinline__ float table_entry(int i, const float* __restrict__ W1,
                                             const float* __restrict__ b1,
                                             const float* __restrict__ W2,
                                             const float* __restrict__ b2) {
    int et = i >> 4, ht = (i >> 2) & 3, tt = i & 3;
    const float* r0 = W1 + et * HIDDEN;
    const float* r1 = W1 + (NUM_EDGE_TYPES + ht) * HIDDEN;
    const float* r2 = W1 + (NUM_EDGE_TYPES + NUM_NODE_TYPES + tt) * HIDDEN;
    float acc = b2[0];
#pragma unroll 8
    for (int k = 0; k < HIDDEN; ++k) {
        float h = r0[k] + r1[k] + r2[k] + b1[k];
        float u = 0.7978845608028654f * (h + 0.044715f * h * h * h);
        float g = 0.5f * h * (1.0f + tanhf(u));
        acc += g * W2[k];
    }
    return 1.0f / (1.0f + expf(-acc));
}

// ---- single-pass partition: LDS hist + fixed-capacity claim + 8-wide scatter ----
__global__ void partition_kernel(const int* __restrict__ src, const int* __restrict__ dst,
                                 const int* __restrict__ etype, int* __restrict__ cursor,
                                 int* __restrict__ pack, int E, int nbk, int cap) {
    __shared__ int hist[MAXB];
    __shared__ int locCur[MAXB];
    for (int i = threadIdx.x; i < nbk; i += PB) hist[i] = 0;
    __syncthreads();
    int start = blockIdx.x * CHUNK;
    int end = min(start + CHUNK, E);
    if (end - start == CHUNK) {               // full chunk: 8 edges/thread, MLP=8
        int j = start + threadIdx.x;
        int d[8], s[8], et[8], slot[8];
#pragma unroll
        for (int k = 0; k < 8; ++k) d[k] = dst[j + k * PB];
#pragma unroll
        for (int k = 0; k < 8; ++k) atomicAdd(&hist[d[k] >> BSHIFT], 1);
        __syncthreads();
        for (int i = threadIdx.x; i < nbk; i += PB) {
            int h = hist[i];
            locCur[i] = h ? i * cap + atomicAdd(&cursor[i], h) : 0;
        }
        __syncthreads();
#pragma unroll
        for (int k = 0; k < 8; ++k) s[k] = src[j + k * PB];
#pragma unroll
        for (int k = 0; k < 8; ++k) et[k] = etype[j + k * PB];
#pragma unroll
        for (int k = 0; k < 8; ++k) slot[k] = atomicAdd(&locCur[d[k] >> BSHIFT], 1);
#pragma unroll
        for (int k = 0; k < 8; ++k)
            pack[slot[k]] = (et[k] << (SRC_BITS + 8)) | ((d[k] & (BNODES - 1)) << SRC_BITS) | s[k];
    } else {                                   // tail chunk
        for (int j = start + threadIdx.x; j < end; j += PB)
            atomicAdd(&hist[dst[j] >> BSHIFT], 1);
        __syncthreads();
        for (int i = threadIdx.x; i < nbk; i += PB) {
            int h = hist[i];
            locCur[i] = h ? i * cap + atomicAdd(&cursor[i], h) : 0;
        }
        __syncthreads();
        for (int j = start + threadIdx.x; j < end; j += PB) {
            int d = dst[j];
            int slot = atomicAdd(&locCur[d >> BSHIFT], 1);
            pack[slot] = (etype[j] << (SRC_BITS + 8)) | ((d & (BNODES - 1)) << SRC_BITS) | src[j];
        }
    }
}

// ---- cooperative mega-kernel: sort bucket into LDS, base + 3 hops with grid.sync ----
// Bucket slice (~16 KB) stays in LDS across all 4 aggregation passes.
__global__ __launch_bounds__(MB, 4)
void mega_kernel(const int* __restrict__ pack, const int* __restrict__ cursor,
                 const int* __restrict__ ntype,
                 const float* __restrict__ W1, const float* __restrict__ b1,
                 const float* __restrict__ W2, const float* __restrict__ b2,
                 float* __restrict__ base, float* __restrict__ bufA,
                 float* __restrict__ bufB, float* __restrict__ out, int N, int cap) {
    cg::grid_group grid = cg::this_grid();
    __shared__ int sortedL[CAPC];
    __shared__ float tbl[TABLE_SIZE];
    __shared__ int nodeCnt[BNODES];
    __shared__ int nodeOff[BNODES + 1];
    __shared__ unsigned char ntLoc[BNODES];
    __shared__ float baseLoc[BNODES];
    int b = blockIdx.x;
    int tid = threadIdx.x;
    int node0 = b << BSHIFT;
    int st = b * cap;
    int c = min(cursor[b], cap);

    for (int i = tid; i < TABLE_SIZE; i += MB) tbl[i] = table_entry(i, W1, b1, W2, b2);
    if (tid < BNODES) {
        nodeCnt[tid] = 0;
        int n = node0 + tid;
        ntLoc[tid] = (n < N) ? (unsigned char)ntype[n] : 0;
    }
    __syncthreads();

    // pass 1: histogram by dstLow
    for (int j = tid; j < c; j += MB)
        atomicAdd(&nodeCnt[(pack[st + j] >> SRC_BITS) & (BNODES - 1)], 1);
    __syncthreads();

    // exclusive scan of 256 counts on wave 0
    if (tid < 64) {
        int lane = tid;
        int v0 = nodeCnt[lane * 4], v1 = nodeCnt[lane * 4 + 1];
        int v2 = nodeCnt[lane * 4 + 2], v3 = nodeCnt[lane * 4 + 3];
        int s = v0 + v1 + v2 + v3;
        int inc = s;
        for (int d = 1; d < 64; d <<= 1) {
            int t = __shfl_up(inc, d, 64);
            if (lane >= d) inc += t;
        }
        int excl = inc - s;
        nodeOff[lane * 4]     = excl;
        nodeOff[lane * 4 + 1] = excl + v0;
        nodeOff[lane * 4 + 2] = excl + v0 + v1;
        nodeOff[lane * 4 + 3] = excl + v0 + v1 + v2;
        if (lane == 63) nodeOff[BNODES] = inc;
    }
    __syncthreads();
    if (tid < BNODES) nodeCnt[tid] = 0;  // reuse as rank cursor
    __syncthreads();

    // pass 2: rank + scatter into LDS (pack slice L2-hot from pass 1); never written back
    for (int j = tid; j < c; j += MB) {
        int p = pack[st + j];
        int dl = (p >> SRC_BITS) & (BNODES - 1);
        int r = atomicAdd(&nodeCnt[dl], 1);
        sortedL[nodeOff[dl] + r] = p;
    }
    __syncthreads();

    // base: 2 lanes per node, segmented sum of table values
    int node = tid >> 1, l = tid & 1;
    int lo = nodeOff[node], hi = nodeOff[node + 1];
    {
        int nt = ntLoc[node];
        float s = 0.0f;
        int j = lo + l;
        for (; j + 2 < hi; j += 4) {
            int p0 = sortedL[j], p1 = sortedL[j + 2];
            s += tbl[((((unsigned)p0) >> (SRC_BITS + 8)) << 4) | (ntype[p0 & SRC_MASK] << 2) | nt]
               + tbl[((((unsigned)p1) >> (SRC_BITS + 8)) << 4) | (ntype[p1 & SRC_MASK] << 2) | nt];
        }
        if (j < hi) {
            int p = sortedL[j];
            s += tbl[((((unsigned)p) >> (SRC_BITS + 8)) << 4) | (ntype[p & SRC_MASK] << 2) | nt];
        }
        s += __shfl_xor(s, 1, 64);
        if (l == 0) {
            baseLoc[node] = s;
            int n = node0 + node;
            if (n < N) base[n] = s;
        }
    }
    grid.sync();

    // hops 2-4: src indices from LDS, prev gathered from L2-resident aggr array
    const float* prevArr[3] = {base, bufA, bufB};
    float* outArr[3] = {bufA, bufB, out};
#pragma unroll
    for (int h = 0; h < 3; ++h) {
        const float* __restrict__ prev = prevArr[h];
        float s = 0.0f;
        int j = lo + l;
        for (; j + 2 < hi; j += 4) {
            int p0 = sortedL[j], p1 = sortedL[j + 2];
            s += prev[p0 & SRC_MASK] + prev[p1 & SRC_MASK];
        }
        if (j < hi) s += prev[sortedL[j] & SRC_MASK];
        s += __shfl_xor(s, 1, 64);
        if (l == 0) {
            int n = node0 + node;
            if (n < N) outArr[h][n] = baseLoc[node] + s;
        }
        if (h < 2) grid.sync();
    }
}

// ================= non-cooperative fallback (R7 path) =================
__global__ void sort_base_kernel(int* __restrict__ pack, const int* __restrict__ cursor,
                                 const int* __restrict__ ntype,
                                 const float* __restrict__ W1, const float* __restrict__ b1,
                                 const float* __restrict__ W2, const float* __restrict__ b2,
                                 float* __restrict__ base, int* __restrict__ nodeOffG,
                                 int N, int cap) {
    __shared__ int sortedL[CAPC];
    __shared__ float tbl[TABLE_SIZE];
    __shared__ int nodeCnt[BNODES];
    __shared__ int nodeOff[BNODES + 1];
    __shared__ unsigned char ntLoc[BNODES];
    int b = blockIdx.x;
    int node0 = b << BSHIFT;
    int tid = threadIdx.x;
    int st = b * cap;
    int c = min(cursor[b], cap);

    if (tid < TABLE_SIZE) tbl[tid] = table_entry(tid, W1, b1, W2, b2);
    if (tid < BNODES) {
        nodeCnt[tid] = 0;
        int n = node0 + tid;
        ntLoc[tid] = (n < N) ? (unsigned char)ntype[n] : 0;
    }
    __syncthreads();
    for (int j = tid; j < c; j += HB)
        atomicAdd(&nodeCnt[(pack[st + j] >> SRC_BITS) & (BNODES - 1)], 1);
    __syncthreads();
    if (tid < 64) {
        int lane = tid;
        int v0 = nodeCnt[lane * 4], v1 = nodeCnt[lane * 4 + 1];
        int v2 = nodeCnt[lane * 4 + 2], v3 = nodeCnt[lane * 4 + 3];
        int s = v0 + v1 + v2 + v3;
        int inc = s;
        for (int d = 1; d < 64; d <<= 1) {
            int t = __shfl_up(inc, d, 64);
            if (lane >= d) inc += t;
        }
        int excl = inc - s;
        nodeOff[lane * 4]     = excl;
        nodeOff[lane * 4 + 1] = excl + v0;
        nodeOff[lane * 4 + 2] = excl + v0 + v1;
        nodeOff[lane * 4 + 3] = excl + v0 + v1 + v2;
        if (lane == 63) nodeOff[BNODES] = inc;
    }
    __syncthreads();
    if (tid < BNODES) nodeCnt[tid] = 0;
    __syncthreads();
    for (int j = tid; j < c; j += HB) {
        int p = pack[st + j];
        int dl = (p >> SRC_BITS) & (BNODES - 1);
        int r = atomicAdd(&nodeCnt[dl], 1);
        sortedL[nodeOff[dl] + r] = p;
    }
    __syncthreads();
    for (int j = tid; j < c; j += HB) pack[st + j] = sortedL[j];
    if (tid < BNODES) nodeOffG[(b << BSHIFT) + tid] = nodeOff[tid];

    int node = tid >> 2, l = tid & 3;
    int lo = nodeOff[node], hi = nodeOff[node + 1];
    int nt = ntLoc[node];
    float s = 0.0f;
    int j = lo + l;
    for (; j + 4 < hi; j += 8) {
        int p0 = sortedL[j], p1 = sortedL[j + 4];
        s += tbl[((((unsigned)p0) >> (SRC_BITS + 8)) << 4) | (ntype[p0 & SRC_MASK] << 2) | nt]
           + tbl[((((unsigned)p1) >> (SRC_BITS + 8)) << 4) | (ntype[p1 & SRC_MASK] << 2) | nt];
    }
    if (j < hi) {
        int p = sortedL[j];
        s += tbl[((((unsigned)p) >> (SRC_BITS + 8)) << 4) | (ntype[p & SRC_MASK] << 2) | nt];
    }
    s += __shfl_xor(s, 1, 64);
    s += __shfl_xor(s, 2, 64);
    int n = node0 + node;
    if (l == 0 && n < N) base[n] = s;
}

__global__ void hop_csr_kernel(const int* __restrict__ pack, const int* __restrict__ nodeOffG,
                               const int* __restrict__ cursor, const float* __restrict__ base,
                               const float* __restrict__ prev, float* __restrict__ out,
                               int N, int cap) {
    __shared__ int off[BNODES + 1];
    int b = blockIdx.x;
    int tid = threadIdx.x;
    int st = b * cap;
    if (tid < BNODES) off[tid] = nodeOffG[(b << BSHIFT) + tid];
    if (tid == 0) off[BNODES] = min(cursor[b], cap);
    __syncthreads();
    int node = tid >> 2, l = tid & 3;
    int lo = off[node], hi = off[node + 1];
    float s = 0.0f;
    int j = st + lo + l;
    int hiG = st + hi;
    for (; j + 4 < hiG; j += 8) {
        int p0 = pack[j], p1 = pack[j + 4];
        s += prev[p0 & SRC_MASK] + prev[p1 & SRC_MASK];
    }
    if (j < hiG) s += prev[pack[j] & SRC_MASK];
    s += __shfl_xor(s, 1, 64);
    s += __shfl_xor(s, 2, 64);
    int n = (b << BSHIFT) + node;
    if (l == 0 && n < N) out[n] = base[n] + s;
}

// ================= edge-parallel atomic fallback (tiny ws) =================
__global__ void table_kernel(const float* __restrict__ W1, const float* __restrict__ b1,
                             const float* __restrict__ W2, const float* __restrict__ b2,
                             float* __restrict__ table) {
    int i = blockIdx.x * blockDim.x + threadIdx.x;
    if (i < TABLE_SIZE) table[i] = table_entry(i, W1, b1, W2, b2);
}

__global__ void edge_base_kernel(const int* __restrict__ src, const int* __restrict__ dst,
                                 const int* __restrict__ etype, const int* __restrict__ ntype,
                                 const float* __restrict__ table, float* __restrict__ base, int E) {
    __shared__ float tbl[TABLE_SIZE];
    for (int i = threadIdx.x; i < TABLE_SIZE; i += blockDim.x) tbl[i] = table[i];
    __syncthreads();
    int e = blockIdx.x * blockDim.x + threadIdx.x;
    if (e >= E) return;
    int s = src[e];
    int d = dst[e];
    int idx = (etype[e] << 4) | (ntype[s] << 2) | ntype[d];
    atomicAdd(base + d, tbl[idx]);
}

__global__ void copy_kernel(const float* __restrict__ in, float* __restrict__ out, int N) {
    int i = blockIdx.x * blockDim.x + threadIdx.x;
    if (i < N) out[i] = in[i];
}

__global__ void edge_hop_kernel(const int* __restrict__ src, const int* __restrict__ dst,
                                const float* __restrict__ prev, float* __restrict__ next, int E) {
    int e = blockIdx.x * blockDim.x + threadIdx.x;
    if (e >= E) return;
    atomicAdd(next + dst[e], prev[src[e]]);
}

extern "C" void kernel_launch(void* const* d_in, const int* in_sizes, int n_in,
                              void* d_out, int out_size, void* d_ws, size_t ws_size,
                              hipStream_t stream) {
    const int* edge_index = (const int*)d_in[0];   // (2, E)
    const int* etype      = (const int*)d_in[1];   // (E,)
    const int* ntype      = (const int*)d_in[2];   // (N,)
    const float* W1       = (const float*)d_in[3];
    const float* b1       = (const float*)d_in[4];
    const float* W2       = (const float*)d_in[5];
    const float* b2       = (const float*)d_in[6];

    const int E = in_sizes[1];
    const int N = in_sizes[2];
    const int* src = edge_index;
    const int* dst = edge_index + E;
    float* out = (float*)d_out;

    const int nbk = (N + BNODES - 1) >> BSHIFT;      // 391 for N=100000
    const int nChunks = (E + CHUNK - 1) / CHUNK;     // 391 for E=1.6M

    int cap = ((E / (nbk > 0 ? nbk : 1)) * 3 / 2 + 255) & ~255;  // 1.5x mean, 256-aligned
    if (cap < 512) cap = 512;
    size_t packElems = (size_t)nbk * cap;

    // ws layout (4B units): pack[nbk*cap] | cursor[MAXB] | nodeOffG[nbk*256]
    //                       | base[N] | bufA[N] | bufB[N]
    size_t need = (packElems + MAXB + (size_t)nbk * BNODES + (size_t)3 * N) * 4 + 256;

    if (ws_size >= need && nbk <= MAXB && cap <= CAPC) {
        int* pack     = (int*)d_ws;
        int* cursor   = pack + packElems;
        int* nodeOffG = cursor + MAXB;
        float* base   = (float*)(nodeOffG + (size_t)nbk * BNODES);
        float* bufA   = base + N;
        float* bufB   = bufA + N;

        hipMemsetAsync(cursor, 0, (size_t)nbk * sizeof(int), stream);
        partition_kernel<<<nChunks, PB, 0, stream>>>(src, dst, etype, cursor, pack, E, nbk, cap);

        int coop = 0, dev = 0;
        hipGetDevice(&dev);
        hipDeviceGetAttribute(&coop, hipDeviceAttributeCooperativeLaunch, dev);

        // co-residency: __launch_bounds__(512,4) -> >=2 blocks/CU -> 512 slots on 256 CUs
        if (coop && nbk <= 512) {
            int N_ = N, cap_ = cap;
            void* args[] = {(void*)&pack, (void*)&cursor, (void*)&ntype,
                            (void*)&W1, (void*)&b1, (void*)&W2, (void*)&b2,
                            (void*)&base, (void*)&bufA, (void*)&bufB, (void*)&out,
                            (void*)&N_, (void*)&cap_};
            hipLaunchCooperativeKernel((const void*)mega_kernel, dim3(nbk), dim3(MB),
                                       args, 0, stream);
        } else {
            sort_base_kernel<<<nbk, HB, 0, stream>>>(pack, cursor, ntype, W1, b1, W2, b2,
                                                     base, nodeOffG, N, cap);
            hop_csr_kernel<<<nbk, HB, 0, stream>>>(pack, nodeOffG, cursor, base, base, bufA, N, cap);
            hop_csr_kernel<<<nbk, HB, 0, stream>>>(pack, nodeOffG, cursor, base, bufA, bufB, N, cap);
            hop_csr_kernel<<<nbk, HB, 0, stream>>>(pack, nodeOffG, cursor, base, bufB, out, N, cap);
        }
    } else {
        // fallback: edge-parallel atomic path
        float* table = (float*)d_ws;
        float* base  = table + 1024;
        float* bufA  = base + N;
        float* bufB  = bufA + N;
        const int eb = (E + 255) / 256;
        const int nb = (N + 255) / 256;

        hipMemsetAsync(base, 0, (size_t)N * sizeof(float), stream);
        table_kernel<<<(TABLE_SIZE + 255) / 256, 256, 0, stream>>>(W1, b1, W2, b2, table);

        edge_base_kernel<<<eb, 256, 0, stream>>>(src, dst, etype, ntype, table, base, E);
        copy_kernel<<<nb, 256, 0, stream>>>(base, bufA, N);
        edge_hop_kernel<<<eb, 256, 0, stream>>>(src, dst, base, bufA, E);
        copy_kernel<<<nb, 256, 0, stream>>>(base, bufB, N);
        edge_hop_kernel<<<eb, 256, 0, stream>>>(src, dst, bufA, bufB, E);
        copy_kernel<<<nb, 256, 0, stream>>>(base, out, N);
        edge_hop_kernel<<<eb, 256, 0, stream>>>(src, dst, bufB, out, E);
    }
}

// Round 9
// 157.194 us; speedup vs baseline: 2.0741x; 2.0741x over previous
//
#include <hip/hip_runtime.h>

#define NUM_EDGE_TYPES 38
#define NUM_NODE_TYPES 4
#define HIDDEN 64
#define TABLE_SIZE (NUM_EDGE_TYPES * NUM_NODE_TYPES * NUM_NODE_TYPES)  // 608
#define SRC_BITS 17
#define SRC_MASK ((1 << SRC_BITS) - 1)   // N_NODES = 100000 < 131072
#define BSHIFT 8                          // 256 dst nodes per bucket
#define BNODES 256
#define MAXB 512                          // supports N up to 131072
#define CHUNK 2048                        // edges per partition block
#define PB 512                            // partition block size
#define HB 1024                           // sort block size
#define CAPC 6144                         // max bucket capacity (LDS sort)
// pack layout: [31]=0 | et[30:25] | dstLow[24:17] | src[16:0]

__device__ __forceinline__ float table_entry(int i, const float* __restrict__ W1,
                                             const float* __restrict__ b1,
                                             const float* __restrict__ W2,
                                             const float* __restrict__ b2) {
    int et = i >> 4, ht = (i >> 2) & 3, tt = i & 3;
    const float* r0 = W1 + et * HIDDEN;
    const float* r1 = W1 + (NUM_EDGE_TYPES + ht) * HIDDEN;
    const float* r2 = W1 + (NUM_EDGE_TYPES + NUM_NODE_TYPES + tt) * HIDDEN;
    float acc = b2[0];
#pragma unroll 8
    for (int k = 0; k < HIDDEN; ++k) {
        float h = r0[k] + r1[k] + r2[k] + b1[k];
        float u = 0.7978845608028654f * (h + 0.044715f * h * h * h);
        float g = 0.5f * h * (1.0f + tanhf(u));
        acc += g * W2[k];
    }
    return 1.0f / (1.0f + expf(-acc));
}

// ---- 608-entry table, computed once ----
__global__ void table_kernel(const float* __restrict__ W1, const float* __restrict__ b1,
                             const float* __restrict__ W2, const float* __restrict__ b2,
                             float* __restrict__ table) {
    int i = blockIdx.x * blockDim.x + threadIdx.x;
    if (i < TABLE_SIZE) table[i] = table_entry(i, W1, b1, W2, b2);
}

// ---- single-pass partition: LDS hist + fixed-capacity claim + 4-wide scatter ----
__global__ void partition_kernel(const int* __restrict__ src, const int* __restrict__ dst,
                                 const int* __restrict__ etype, int* __restrict__ cursor,
                                 int* __restrict__ pack, int E, int nbk, int cap) {
    __shared__ int hist[MAXB];
    __shared__ int locCur[MAXB];
    for (int i = threadIdx.x; i < nbk; i += PB) hist[i] = 0;
    __syncthreads();
    int start = blockIdx.x * CHUNK;
    int end = min(start + CHUNK, E);
    if (end - start == CHUNK) {               // full chunk: 4 edges/thread, MLP=4
        int j = start + threadIdx.x;
        int d[4], s[4], et[4], slot[4];
#pragma unroll
        for (int k = 0; k < 4; ++k) d[k] = dst[j + k * PB];
#pragma unroll
        for (int k = 0; k < 4; ++k) atomicAdd(&hist[d[k] >> BSHIFT], 1);
        __syncthreads();
        for (int i = threadIdx.x; i < nbk; i += PB) {
            int h = hist[i];
            locCur[i] = h ? i * cap + atomicAdd(&cursor[i], h) : 0;
        }
        __syncthreads();
#pragma unroll
        for (int k = 0; k < 4; ++k) s[k] = src[j + k * PB];
#pragma unroll
        for (int k = 0; k < 4; ++k) et[k] = etype[j + k * PB];
#pragma unroll
        for (int k = 0; k < 4; ++k) slot[k] = atomicAdd(&locCur[d[k] >> BSHIFT], 1);
#pragma unroll
        for (int k = 0; k < 4; ++k)
            pack[slot[k]] = (et[k] << (SRC_BITS + 8)) | ((d[k] & (BNODES - 1)) << SRC_BITS) | s[k];
    } else {                                   // tail chunk
        for (int j = start + threadIdx.x; j < end; j += PB)
            atomicAdd(&hist[dst[j] >> BSHIFT], 1);
        __syncthreads();
        for (int i = threadIdx.x; i < nbk; i += PB) {
            int h = hist[i];
            locCur[i] = h ? i * cap + atomicAdd(&cursor[i], h) : 0;
        }
        __syncthreads();
        for (int j = start + threadIdx.x; j < end; j += PB) {
            int d = dst[j];
            int slot = atomicAdd(&locCur[d >> BSHIFT], 1);
            pack[slot] = (etype[j] << (SRC_BITS + 8)) | ((d & (BNODES - 1)) << SRC_BITS) | src[j];
        }
    }
}

// ---- sort bucket by dstLow (LDS counting sort, write-back), emit per-node offsets,
// and compute base[] via node-parallel segmented sums (4 lanes/node, no atomics). ----
__global__ void sort_base_kernel(int* __restrict__ pack, const int* __restrict__ cursor,
                                 const int* __restrict__ ntype, const float* __restrict__ table,
                                 float* __restrict__ base, int* __restrict__ nodeOffG,
                                 int N, int cap) {
    __shared__ int sortedL[CAPC];
    __shared__ float tbl[TABLE_SIZE];
    __shared__ int nodeCnt[BNODES];
    __shared__ int nodeOff[BNODES + 1];
    __shared__ unsigned char ntLoc[BNODES];
    int b = blockIdx.x;
    int node0 = b << BSHIFT;
    int tid = threadIdx.x;
    int st = b * cap;
    int c = min(cursor[b], cap);

    if (tid < TABLE_SIZE) tbl[tid] = table[tid];
    if (tid < BNODES) {
        nodeCnt[tid] = 0;
        int n = node0 + tid;
        ntLoc[tid] = (n < N) ? (unsigned char)ntype[n] : 0;
    }
    __syncthreads();

    // pass 1: histogram by dstLow
    for (int j = tid; j < c; j += HB)
        atomicAdd(&nodeCnt[(pack[st + j] >> SRC_BITS) & (BNODES - 1)], 1);
    __syncthreads();

    // exclusive scan of 256 counts on wave 0
    if (tid < 64) {
        int lane = tid;
        int v0 = nodeCnt[lane * 4], v1 = nodeCnt[lane * 4 + 1];
        int v2 = nodeCnt[lane * 4 + 2], v3 = nodeCnt[lane * 4 + 3];
        int s = v0 + v1 + v2 + v3;
        int inc = s;
        for (int d = 1; d < 64; d <<= 1) {
            int t = __shfl_up(inc, d, 64);
            if (lane >= d) inc += t;
        }
        int excl = inc - s;
        nodeOff[lane * 4]     = excl;
        nodeOff[lane * 4 + 1] = excl + v0;
        nodeOff[lane * 4 + 2] = excl + v0 + v1;
        nodeOff[lane * 4 + 3] = excl + v0 + v1 + v2;
        if (lane == 63) nodeOff[BNODES] = inc;
    }
    __syncthreads();
    if (tid < BNODES) nodeCnt[tid] = 0;  // reuse as rank cursor
    __syncthreads();

    // pass 2: rank + scatter into LDS (pack slice L1-hot from pass 1)
    for (int j = tid; j < c; j += HB) {
        int p = pack[st + j];
        int dl = (p >> SRC_BITS) & (BNODES - 1);
        int r = atomicAdd(&nodeCnt[dl], 1);
        sortedL[nodeOff[dl] + r] = p;
    }
    __syncthreads();

    // write sorted slice back + per-node offsets
    for (int j = tid; j < c; j += HB) pack[st + j] = sortedL[j];
    if (tid < BNODES) nodeOffG[(b << BSHIFT) + tid] = nodeOff[tid];

    // base: 4 lanes/node segmented sum of table values
    int node = tid >> 2, l = tid & 3;
    int lo = nodeOff[node], hi = nodeOff[node + 1];
    int nt = ntLoc[node];
    float s = 0.0f;
    int j = lo + l;
    for (; j + 4 < hi; j += 8) {
        int p0 = sortedL[j], p1 = sortedL[j + 4];
        s += tbl[((((unsigned)p0) >> (SRC_BITS + 8)) << 4) | (ntype[p0 & SRC_MASK] << 2) | nt]
           + tbl[((((unsigned)p1) >> (SRC_BITS + 8)) << 4) | (ntype[p1 & SRC_MASK] << 2) | nt];
    }
    if (j < hi) {
        int p = sortedL[j];
        s += tbl[((((unsigned)p) >> (SRC_BITS + 8)) << 4) | (ntype[p & SRC_MASK] << 2) | nt];
    }
    s += __shfl_xor(s, 1, 64);
    s += __shfl_xor(s, 2, 64);
    int n = node0 + node;
    if (l == 0 && n < N) base[n] = s;
}

// ---- hops 2-4: CSR segmented sums, 2 blocks per bucket (128 nodes each),
// 4 lanes/node, 2-wide unroll. Atomic-free. ----
__global__ __launch_bounds__(512)
void hop_csr_kernel(const int* __restrict__ pack, const int* __restrict__ nodeOffG,
                    const int* __restrict__ cursor, const float* __restrict__ base,
                    const float* __restrict__ prev, float* __restrict__ out,
                    int N, int cap) {
    __shared__ int off[129];
    int blk = blockIdx.x;
    int b = blk >> 1;
    int half = blk & 1;
    int tid = threadIdx.x;
    int st = b * cap;
    int nodeBase = (b << BSHIFT) + half * 128;
    if (tid < 128) off[tid] = nodeOffG[(b << BSHIFT) + half * 128 + tid];
    else if (tid == 128)
        off[128] = half ? min(cursor[b], cap) : nodeOffG[(b << BSHIFT) + 128];
    __syncthreads();
    int node = tid >> 2, l = tid & 3;   // node in 0..127
    int lo = off[node], hi = off[node + 1];
    float s = 0.0f;
    int j = st + lo + l;
    int hiG = st + hi;
    for (; j + 4 < hiG; j += 8) {
        int p0 = pack[j], p1 = pack[j + 4];
        s += prev[p0 & SRC_MASK] + prev[p1 & SRC_MASK];
    }
    if (j < hiG) s += prev[pack[j] & SRC_MASK];
    s += __shfl_xor(s, 1, 64);
    s += __shfl_xor(s, 2, 64);
    int n = nodeBase + node;
    if (l == 0 && n < N) out[n] = base[n] + s;
}

// ================= edge-parallel atomic fallback (tiny ws) =================
__global__ void edge_base_kernel(const int* __restrict__ src, const int* __restrict__ dst,
                                 const int* __restrict__ etype, const int* __restrict__ ntype,
                                 const float* __restrict__ table, float* __restrict__ base, int E) {
    __shared__ float tbl[TABLE_SIZE];
    for (int i = threadIdx.x; i < TABLE_SIZE; i += blockDim.x) tbl[i] = table[i];
    __syncthreads();
    int e = blockIdx.x * blockDim.x + threadIdx.x;
    if (e >= E) return;
    int s = src[e];
    int d = dst[e];
    int idx = (etype[e] << 4) | (ntype[s] << 2) | ntype[d];
    atomicAdd(base + d, tbl[idx]);
}

__global__ void copy_kernel(const float* __restrict__ in, float* __restrict__ out, int N) {
    int i = blockIdx.x * blockDim.x + threadIdx.x;
    if (i < N) out[i] = in[i];
}

__global__ void edge_hop_kernel(const int* __restrict__ src, const int* __restrict__ dst,
                                const float* __restrict__ prev, float* __restrict__ next, int E) {
    int e = blockIdx.x * blockDim.x + threadIdx.x;
    if (e >= E) return;
    atomicAdd(next + dst[e], prev[src[e]]);
}

extern "C" void kernel_launch(void* const* d_in, const int* in_sizes, int n_in,
                              void* d_out, int out_size, void* d_ws, size_t ws_size,
                              hipStream_t stream) {
    const int* edge_index = (const int*)d_in[0];   // (2, E)
    const int* etype      = (const int*)d_in[1];   // (E,)
    const int* ntype      = (const int*)d_in[2];   // (N,)
    const float* W1       = (const float*)d_in[3];
    const float* b1       = (const float*)d_in[4];
    const float* W2       = (const float*)d_in[5];
    const float* b2       = (const float*)d_in[6];

    const int E = in_sizes[1];
    const int N = in_sizes[2];
    const int* src = edge_index;
    const int* dst = edge_index + E;
    float* out = (float*)d_out;

    const int nbk = (N + BNODES - 1) >> BSHIFT;      // 391 for N=100000
    const int nChunks = (E + CHUNK - 1) / CHUNK;     // 782 for E=1.6M

    int cap = ((E / (nbk > 0 ? nbk : 1)) * 3 / 2 + 255) & ~255;  // 1.5x mean, 256-aligned
    if (cap < 512) cap = 512;
    size_t packElems = (size_t)nbk * cap;

    // ws layout (4B units): pack[nbk*cap] | cursor[MAXB] | nodeOffG[nbk*256]
    //                       | table[1024] | base[N] | bufA[N] | bufB[N]
    size_t need = (packElems + MAXB + (size_t)nbk * BNODES + 1024 + (size_t)3 * N) * 4 + 256;

    if (ws_size >= need && nbk <= MAXB && cap <= CAPC) {
        int* pack     = (int*)d_ws;
        int* cursor   = pack + packElems;
        int* nodeOffG = cursor + MAXB;
        float* table  = (float*)(nodeOffG + (size_t)nbk * BNODES);
        float* base   = table + 1024;
        float* bufA   = base + N;
        float* bufB   = bufA + N;

        hipMemsetAsync(cursor, 0, (size_t)nbk * sizeof(int), stream);
        table_kernel<<<(TABLE_SIZE + 255) / 256, 256, 0, stream>>>(W1, b1, W2, b2, table);
        partition_kernel<<<nChunks, PB, 0, stream>>>(src, dst, etype, cursor, pack, E, nbk, cap);
        sort_base_kernel<<<nbk, HB, 0, stream>>>(pack, cursor, ntype, table, base, nodeOffG, N, cap);
        hop_csr_kernel<<<2 * nbk, 512, 0, stream>>>(pack, nodeOffG, cursor, base, base, bufA, N, cap);
        hop_csr_kernel<<<2 * nbk, 512, 0, stream>>>(pack, nodeOffG, cursor, base, bufA, bufB, N, cap);
        hop_csr_kernel<<<2 * nbk, 512, 0, stream>>>(pack, nodeOffG, cursor, base, bufB, out, N, cap);
    } else {
        // fallback: edge-parallel atomic path
        float* table = (float*)d_ws;
        float* base  = table + 1024;
        float* bufA  = base + N;
        float* bufB  = bufA + N;
        const int eb = (E + 255) / 256;
        const int nb = (N + 255) / 256;

        hipMemsetAsync(base, 0, (size_t)N * sizeof(float), stream);
        table_kernel<<<(TABLE_SIZE + 255) / 256, 256, 0, stream>>>(W1, b1, W2, b2, table);

        edge_base_kernel<<<eb, 256, 0, stream>>>(src, dst, etype, ntype, table, base, E);
        copy_kernel<<<nb, 256, 0, stream>>>(base, bufA, N);
        edge_hop_kernel<<<eb, 256, 0, stream>>>(src, dst, base, bufA, E);
        copy_kernel<<<nb, 256, 0, stream>>>(base, bufB, N);
        edge_hop_kernel<<<eb, 256, 0, stream>>>(src, dst, bufA, bufB, E);
        copy_kernel<<<nb, 256, 0, stream>>>(base, out, N);
        edge_hop_kernel<<<eb, 256, 0, stream>>>(src, dst, bufB, out, E);
    }
}

// Round 10
// 149.962 us; speedup vs baseline: 2.1741x; 1.0482x over previous
//
#include <hip/hip_runtime.h>

#define NUM_EDGE_TYPES 38
#define NUM_NODE_TYPES 4
#define HIDDEN 64
#define TABLE_SIZE (NUM_EDGE_TYPES * NUM_NODE_TYPES * NUM_NODE_TYPES)  // 608
#define SRC_BITS 17
#define SRC_MASK ((1 << SRC_BITS) - 1)   // N_NODES = 100000 < 131072
#define BSHIFT 8                          // 256 dst nodes per bucket
#define BNODES 256
#define MAXB 512                          // supports N up to 131072
#define PB 512                            // partition block size
#define CHUNK (PB * 4)                    // 2048 edges per partition block (int4/thread)
#define HB 1024                           // sort block size
#define CAPC 6144                         // max bucket capacity (LDS sort)
// pack layout: [31]=0 | et[30:25] | dstLow[24:17] | src[16:0]

__device__ __forceinline__ float table_entry(int i, const float* __restrict__ W1,
                                             const float* __restrict__ b1,
                                             const float* __restrict__ W2,
                                             const float* __restrict__ b2) {
    int et = i >> 4, ht = (i >> 2) & 3, tt = i & 3;
    const float* r0 = W1 + et * HIDDEN;
    const float* r1 = W1 + (NUM_EDGE_TYPES + ht) * HIDDEN;
    const float* r2 = W1 + (NUM_EDGE_TYPES + NUM_NODE_TYPES + tt) * HIDDEN;
    float acc = b2[0];
#pragma unroll 8
    for (int k = 0; k < HIDDEN; ++k) {
        float h = r0[k] + r1[k] + r2[k] + b1[k];
        float u = 0.7978845608028654f * (h + 0.044715f * h * h * h);
        float g = 0.5f * h * (1.0f + tanhf(u));
        acc += g * W2[k];
    }
    return 1.0f / (1.0f + expf(-acc));
}

// ---- table + cursor zeroing in one tiny launch ----
__global__ void init_kernel(const float* __restrict__ W1, const float* __restrict__ b1,
                            const float* __restrict__ W2, const float* __restrict__ b2,
                            float* __restrict__ table, int* __restrict__ cursor) {
    int t = threadIdx.x;
    if (t < MAXB) cursor[t] = 0;
    if (t < TABLE_SIZE) table[t] = table_entry(t, W1, b1, W2, b2);
}

// standalone table (fallback path)
__global__ void table_kernel(const float* __restrict__ W1, const float* __restrict__ b1,
                             const float* __restrict__ W2, const float* __restrict__ b2,
                             float* __restrict__ table) {
    int i = blockIdx.x * blockDim.x + threadIdx.x;
    if (i < TABLE_SIZE) table[i] = table_entry(i, W1, b1, W2, b2);
}

// ---- single-pass partition: int4 edge loads, LDS hist, fixed-capacity claim, scatter ----
__global__ void partition_kernel(const int* __restrict__ src, const int* __restrict__ dst,
                                 const int* __restrict__ etype, int* __restrict__ cursor,
                                 int* __restrict__ pack, int E, int nbk, int cap) {
    __shared__ int hist[MAXB];
    __shared__ int locCur[MAXB];
    for (int i = threadIdx.x; i < nbk; i += PB) hist[i] = 0;
    __syncthreads();
    int start = blockIdx.x * CHUNK;
    int end = min(start + CHUNK, E);
    if (end - start == CHUNK) {               // full chunk: one int4 of edges per thread
        int j = start + threadIdx.x * 4;
        int4 d  = *(const int4*)(dst + j);
        int4 s  = *(const int4*)(src + j);
        int4 et = *(const int4*)(etype + j);
        atomicAdd(&hist[d.x >> BSHIFT], 1);
        atomicAdd(&hist[d.y >> BSHIFT], 1);
        atomicAdd(&hist[d.z >> BSHIFT], 1);
        atomicAdd(&hist[d.w >> BSHIFT], 1);
        __syncthreads();
        for (int i = threadIdx.x; i < nbk; i += PB) {
            int h = hist[i];
            locCur[i] = h ? i * cap + atomicAdd(&cursor[i], h) : 0;
        }
        __syncthreads();
        int t0 = atomicAdd(&locCur[d.x >> BSHIFT], 1);
        int t1 = atomicAdd(&locCur[d.y >> BSHIFT], 1);
        int t2 = atomicAdd(&locCur[d.z >> BSHIFT], 1);
        int t3 = atomicAdd(&locCur[d.w >> BSHIFT], 1);
        pack[t0] = (et.x << (SRC_BITS + 8)) | ((d.x & (BNODES - 1)) << SRC_BITS) | s.x;
        pack[t1] = (et.y << (SRC_BITS + 8)) | ((d.y & (BNODES - 1)) << SRC_BITS) | s.y;
        pack[t2] = (et.z << (SRC_BITS + 8)) | ((d.z & (BNODES - 1)) << SRC_BITS) | s.z;
        pack[t3] = (et.w << (SRC_BITS + 8)) | ((d.w & (BNODES - 1)) << SRC_BITS) | s.w;
    } else {                                   // tail chunk: scalar
        for (int j = start + threadIdx.x; j < end; j += PB)
            atomicAdd(&hist[dst[j] >> BSHIFT], 1);
        __syncthreads();
        for (int i = threadIdx.x; i < nbk; i += PB) {
            int h = hist[i];
            locCur[i] = h ? i * cap + atomicAdd(&cursor[i], h) : 0;
        }
        __syncthreads();
        for (int j = start + threadIdx.x; j < end; j += PB) {
            int d = dst[j];
            int slot = atomicAdd(&locCur[d >> BSHIFT], 1);
            pack[slot] = (etype[j] << (SRC_BITS + 8)) | ((d & (BNODES - 1)) << SRC_BITS) | src[j];
        }
    }
}

// ---- sort bucket by dstLow: ONE int4 global read into LDS (hist fused), LDS->LDS
// rank-scatter, int4 write-back, per-node offsets, base[] segmented sums. ----
__global__ void sort_base_kernel(int* __restrict__ pack, const int* __restrict__ cursor,
                                 const int* __restrict__ ntype, const float* __restrict__ table,
                                 float* __restrict__ base, int* __restrict__ nodeOffG,
                                 int N, int cap) {
    __shared__ int rawL[CAPC];
    __shared__ int sortedL[CAPC];
    __shared__ float tbl[TABLE_SIZE];
    __shared__ int nodeCnt[BNODES];
    __shared__ int nodeOff[BNODES + 1];
    __shared__ unsigned char ntLoc[BNODES];
    int b = blockIdx.x;
    int node0 = b << BSHIFT;
    int tid = threadIdx.x;
    int st = b * cap;                 // cap is 256-aligned -> st*4 bytes is 16B-aligned
    int c = min(cursor[b], cap);

    if (tid < TABLE_SIZE) tbl[tid] = table[tid];
    if (tid < BNODES) {
        nodeCnt[tid] = 0;
        int n = node0 + tid;
        ntLoc[tid] = (n < N) ? (unsigned char)ntype[n] : 0;
    }
    __syncthreads();

    // pass 1: int4 load into rawL + histogram by dstLow (single global read)
    int c4 = c & ~3;
    for (int j = tid * 4; j < c4; j += HB * 4) {
        int4 v = *(const int4*)(pack + st + j);
        *(int4*)(rawL + j) = v;
        atomicAdd(&nodeCnt[(v.x >> SRC_BITS) & (BNODES - 1)], 1);
        atomicAdd(&nodeCnt[(v.y >> SRC_BITS) & (BNODES - 1)], 1);
        atomicAdd(&nodeCnt[(v.z >> SRC_BITS) & (BNODES - 1)], 1);
        atomicAdd(&nodeCnt[(v.w >> SRC_BITS) & (BNODES - 1)], 1);
    }
    for (int j = c4 + tid; j < c; j += HB) {
        int p = pack[st + j];
        rawL[j] = p;
        atomicAdd(&nodeCnt[(p >> SRC_BITS) & (BNODES - 1)], 1);
    }
    __syncthreads();

    // exclusive scan of 256 counts on wave 0
    if (tid < 64) {
        int lane = tid;
        int v0 = nodeCnt[lane * 4], v1 = nodeCnt[lane * 4 + 1];
        int v2 = nodeCnt[lane * 4 + 2], v3 = nodeCnt[lane * 4 + 3];
        int s = v0 + v1 + v2 + v3;
        int inc = s;
        for (int d = 1; d < 64; d <<= 1) {
            int t = __shfl_up(inc, d, 64);
            if (lane >= d) inc += t;
        }
        int excl = inc - s;
        nodeOff[lane * 4]     = excl;
        nodeOff[lane * 4 + 1] = excl + v0;
        nodeOff[lane * 4 + 2] = excl + v0 + v1;
        nodeOff[lane * 4 + 3] = excl + v0 + v1 + v2;
        if (lane == 63) nodeOff[BNODES] = inc;
    }
    __syncthreads();
    if (tid < BNODES) nodeCnt[tid] = 0;  // reuse as rank cursor
    __syncthreads();

    // pass 2: rank + scatter LDS -> LDS
    for (int j = tid; j < c; j += HB) {
        int p = rawL[j];
        int dl = (p >> SRC_BITS) & (BNODES - 1);
        int r = atomicAdd(&nodeCnt[dl], 1);
        sortedL[nodeOff[dl] + r] = p;
    }
    __syncthreads();

    // int4 write-back of sorted slice + per-node offsets
    for (int j = tid * 4; j < c4; j += HB * 4)
        *(int4*)(pack + st + j) = *(const int4*)(sortedL + j);
    for (int j = c4 + tid; j < c; j += HB) pack[st + j] = sortedL[j];
    if (tid < BNODES) nodeOffG[(b << BSHIFT) + tid] = nodeOff[tid];

    // base: 4 lanes/node segmented sum of table values
    int node = tid >> 2, l = tid & 3;
    int lo = nodeOff[node], hi = nodeOff[node + 1];
    int nt = ntLoc[node];
    float s = 0.0f;
    int j = lo + l;
    for (; j + 4 < hi; j += 8) {
        int p0 = sortedL[j], p1 = sortedL[j + 4];
        s += tbl[((((unsigned)p0) >> (SRC_BITS + 8)) << 4) | (ntype[p0 & SRC_MASK] << 2) | nt]
           + tbl[((((unsigned)p1) >> (SRC_BITS + 8)) << 4) | (ntype[p1 & SRC_MASK] << 2) | nt];
    }
    if (j < hi) {
        int p = sortedL[j];
        s += tbl[((((unsigned)p) >> (SRC_BITS + 8)) << 4) | (ntype[p & SRC_MASK] << 2) | nt];
    }
    s += __shfl_xor(s, 1, 64);
    s += __shfl_xor(s, 2, 64);
    int n = node0 + node;
    if (l == 0 && n < N) base[n] = s;
}

// ---- hops 2-4: CSR segmented sums, 2 blocks per bucket (128 nodes each),
// 4 lanes/node, 4-wide gather unroll. Atomic-free. ----
__global__ __launch_bounds__(512)
void hop_csr_kernel(const int* __restrict__ pack, const int* __restrict__ nodeOffG,
                    const int* __restrict__ cursor, const float* __restrict__ base,
                    const float* __restrict__ prev, float* __restrict__ out,
                    int N, int cap) {
    __shared__ int off[129];
    int blk = blockIdx.x;
    int b = blk >> 1;
    int half = blk & 1;
    int tid = threadIdx.x;
    int st = b * cap;
    int nodeBase = (b << BSHIFT) + half * 128;
    if (tid < 128) off[tid] = nodeOffG[(b << BSHIFT) + half * 128 + tid];
    else if (tid == 128)
        off[128] = half ? min(cursor[b], cap) : nodeOffG[(b << BSHIFT) + 128];
    __syncthreads();
    int node = tid >> 2, l = tid & 3;   // node in 0..127
    int lo = off[node], hi = off[node + 1];
    float s = 0.0f;
    int j = st + lo + l;
    int hiG = st + hi;
    for (; j + 12 < hiG; j += 16) {
        int p0 = pack[j], p1 = pack[j + 4], p2 = pack[j + 8], p3 = pack[j + 12];
        s += prev[p0 & SRC_MASK] + prev[p1 & SRC_MASK]
           + prev[p2 & SRC_MASK] + prev[p3 & SRC_MASK];
    }
    for (; j < hiG; j += 4) s += prev[pack[j] & SRC_MASK];
    s += __shfl_xor(s, 1, 64);
    s += __shfl_xor(s, 2, 64);
    int n = nodeBase + node;
    if (l == 0 && n < N) out[n] = base[n] + s;
}

// ================= edge-parallel atomic fallback (tiny ws) =================
__global__ void edge_base_kernel(const int* __restrict__ src, const int* __restrict__ dst,
                                 const int* __restrict__ etype, const int* __restrict__ ntype,
                                 const float* __restrict__ table, float* __restrict__ base, int E) {
    __shared__ float tbl[TABLE_SIZE];
    for (int i = threadIdx.x; i < TABLE_SIZE; i += blockDim.x) tbl[i] = table[i];
    __syncthreads();
    int e = blockIdx.x * blockDim.x + threadIdx.x;
    if (e >= E) return;
    int s = src[e];
    int d = dst[e];
    int idx = (etype[e] << 4) | (ntype[s] << 2) | ntype[d];
    atomicAdd(base + d, tbl[idx]);
}

__global__ void copy_kernel(const float* __restrict__ in, float* __restrict__ out, int N) {
    int i = blockIdx.x * blockDim.x + threadIdx.x;
    if (i < N) out[i] = in[i];
}

__global__ void edge_hop_kernel(const int* __restrict__ src, const int* __restrict__ dst,
                                const float* __restrict__ prev, float* __restrict__ next, int E) {
    int e = blockIdx.x * blockDim.x + threadIdx.x;
    if (e >= E) return;
    atomicAdd(next + dst[e], prev[src[e]]);
}

extern "C" void kernel_launch(void* const* d_in, const int* in_sizes, int n_in,
                              void* d_out, int out_size, void* d_ws, size_t ws_size,
                              hipStream_t stream) {
    const int* edge_index = (const int*)d_in[0];   // (2, E)
    const int* etype      = (const int*)d_in[1];   // (E,)
    const int* ntype      = (const int*)d_in[2];   // (N,)
    const float* W1       = (const float*)d_in[3];
    const float* b1       = (const float*)d_in[4];
    const float* W2       = (const float*)d_in[5];
    const float* b2       = (const float*)d_in[6];

    const int E = in_sizes[1];
    const int N = in_sizes[2];
    const int* src = edge_index;
    const int* dst = edge_index + E;
    float* out = (float*)d_out;

    const int nbk = (N + BNODES - 1) >> BSHIFT;      // 391 for N=100000
    const int nChunks = (E + CHUNK - 1) / CHUNK;     // 782 for E=1.6M

    int cap = ((E / (nbk > 0 ? nbk : 1)) * 3 / 2 + 255) & ~255;  // 1.5x mean, 256-aligned
    if (cap < 512) cap = 512;
    size_t packElems = (size_t)nbk * cap;

    // ws layout (4B units): pack[nbk*cap] | cursor[MAXB] | nodeOffG[nbk*256]
    //                       | table[1024] | base[N] | bufA[N] | bufB[N]
    size_t need = (packElems + MAXB + (size_t)nbk * BNODES + 1024 + (size_t)3 * N) * 4 + 256;

    if (ws_size >= need && nbk <= MAXB && cap <= CAPC) {
        int* pack     = (int*)d_ws;
        int* cursor   = pack + packElems;
        int* nodeOffG = cursor + MAXB;
        float* table  = (float*)(nodeOffG + (size_t)nbk * BNODES);
        float* base   = table + 1024;
        float* bufA   = base + N;
        float* bufB   = bufA + N;

        init_kernel<<<1, 1024, 0, stream>>>(W1, b1, W2, b2, table, cursor);
        partition_kernel<<<nChunks, PB, 0, stream>>>(src, dst, etype, cursor, pack, E, nbk, cap);
        sort_base_kernel<<<nbk, HB, 0, stream>>>(pack, cursor, ntype, table, base, nodeOffG, N, cap);
        hop_csr_kernel<<<2 * nbk, 512, 0, stream>>>(pack, nodeOffG, cursor, base, base, bufA, N, cap);
        hop_csr_kernel<<<2 * nbk, 512, 0, stream>>>(pack, nodeOffG, cursor, base, bufA, bufB, N, cap);
        hop_csr_kernel<<<2 * nbk, 512, 0, stream>>>(pack, nodeOffG, cursor, base, bufB, out, N, cap);
    } else {
        // fallback: edge-parallel atomic path
        float* table = (float*)d_ws;
        float* base  = table + 1024;
        float* bufA  = base + N;
        float* bufB  = bufA + N;
        const int eb = (E + 255) / 256;
        const int nb = (N + 255) / 256;

        hipMemsetAsync(base, 0, (size_t)N * sizeof(float), stream);
        table_kernel<<<(TABLE_SIZE + 255) / 256, 256, 0, stream>>>(W1, b1, W2, b2, table);

        edge_base_kernel<<<eb, 256, 0, stream>>>(src, dst, etype, ntype, table, base, E);
        copy_kernel<<<nb, 256, 0, stream>>>(base, bufA, N);
        edge_hop_kernel<<<eb, 256, 0, stream>>>(src, dst, base, bufA, E);
        copy_kernel<<<nb, 256, 0, stream>>>(base, bufB, N);
        edge_hop_kernel<<<eb, 256, 0, stream>>>(src, dst, bufA, bufB, E);
        copy_kernel<<<nb, 256, 0, stream>>>(base, out, N);
        edge_hop_kernel<<<eb, 256, 0, stream>>>(src, dst, bufB, out, E);
    }
}

// Round 11
// 144.722 us; speedup vs baseline: 2.2528x; 1.0362x over previous
//
#include <hip/hip_runtime.h>

#define NUM_EDGE_TYPES 38
#define NUM_NODE_TYPES 4
#define HIDDEN 64
#define TABLE_SIZE (NUM_EDGE_TYPES * NUM_NODE_TYPES * NUM_NODE_TYPES)  // 608
#define SRC_BITS 17
#define SRC_MASK ((1 << SRC_BITS) - 1)   // N_NODES = 100000 < 131072
#define BSHIFT 8                          // 256 dst nodes per bucket
#define BNODES 256
#define MAXB 512                          // supports N up to 131072
#define PB 512                            // partition block size
#define CHUNK (PB * 8)                    // 4096 edges per partition block (2x int4/thread)
#define HB 1024                           // sort block size
#define CAPC 6144                         // max bucket capacity (LDS sort)
// pack layout: [31]=0 | et[30:25] | dstLow[24:17] | src[16:0]

__device__ __forceinline__ float table_entry(int i, const float* __restrict__ W1,
                                             const float* __restrict__ b1,
                                             const float* __restrict__ W2,
                                             const float* __restrict__ b2) {
    int et = i >> 4, ht = (i >> 2) & 3, tt = i & 3;
    const float* r0 = W1 + et * HIDDEN;
    const float* r1 = W1 + (NUM_EDGE_TYPES + ht) * HIDDEN;
    const float* r2 = W1 + (NUM_EDGE_TYPES + NUM_NODE_TYPES + tt) * HIDDEN;
    float acc = b2[0];
#pragma unroll 8
    for (int k = 0; k < HIDDEN; ++k) {
        float h = r0[k] + r1[k] + r2[k] + b1[k];
        float u = 0.7978845608028654f * (h + 0.044715f * h * h * h);
        float g = 0.5f * h * (1.0f + tanhf(u));
        acc += g * W2[k];
    }
    return 1.0f / (1.0f + expf(-acc));
}

// ---- table + cursor zeroing in one tiny launch ----
__global__ void init_kernel(const float* __restrict__ W1, const float* __restrict__ b1,
                            const float* __restrict__ W2, const float* __restrict__ b2,
                            float* __restrict__ table, int* __restrict__ cursor) {
    int t = threadIdx.x;
    if (t < MAXB) cursor[t] = 0;
    if (t < TABLE_SIZE) table[t] = table_entry(t, W1, b1, W2, b2);
}

// standalone table (fallback path)
__global__ void table_kernel(const float* __restrict__ W1, const float* __restrict__ b1,
                             const float* __restrict__ W2, const float* __restrict__ b2,
                             float* __restrict__ table) {
    int i = blockIdx.x * blockDim.x + threadIdx.x;
    if (i < TABLE_SIZE) table[i] = table_entry(i, W1, b1, W2, b2);
}

// ---- single-pass partition: 8 edges/thread (2x int4), LDS hist, one claim phase,
// scatter. CHUNK=4096 halves the number of global cursor-claim phases vs 2048. ----
__global__ void partition_kernel(const int* __restrict__ src, const int* __restrict__ dst,
                                 const int* __restrict__ etype, int* __restrict__ cursor,
                                 int* __restrict__ pack, int E, int nbk, int cap) {
    __shared__ int hist[MAXB];
    __shared__ int locCur[MAXB];
    for (int i = threadIdx.x; i < nbk; i += PB) hist[i] = 0;
    __syncthreads();
    int start = blockIdx.x * CHUNK;
    int end = min(start + CHUNK, E);
    if (end - start == CHUNK) {               // full chunk: 8 edges/thread
        int j0 = start + threadIdx.x * 4;            // edges [j0, j0+3]
        int j1 = start + PB * 4 + threadIdx.x * 4;   // edges [j1, j1+3]
        int4 da = *(const int4*)(dst + j0);
        int4 db = *(const int4*)(dst + j1);
        atomicAdd(&hist[da.x >> BSHIFT], 1);
        atomicAdd(&hist[da.y >> BSHIFT], 1);
        atomicAdd(&hist[da.z >> BSHIFT], 1);
        atomicAdd(&hist[da.w >> BSHIFT], 1);
        atomicAdd(&hist[db.x >> BSHIFT], 1);
        atomicAdd(&hist[db.y >> BSHIFT], 1);
        atomicAdd(&hist[db.z >> BSHIFT], 1);
        atomicAdd(&hist[db.w >> BSHIFT], 1);
        int4 sa = *(const int4*)(src + j0);
        int4 sb = *(const int4*)(src + j1);
        int4 ea = *(const int4*)(etype + j0);
        int4 eb = *(const int4*)(etype + j1);
        __syncthreads();
        for (int i = threadIdx.x; i < nbk; i += PB) {
            int h = hist[i];
            locCur[i] = h ? i * cap + atomicAdd(&cursor[i], h) : 0;
        }
        __syncthreads();
        int t0 = atomicAdd(&locCur[da.x >> BSHIFT], 1);
        int t1 = atomicAdd(&locCur[da.y >> BSHIFT], 1);
        int t2 = atomicAdd(&locCur[da.z >> BSHIFT], 1);
        int t3 = atomicAdd(&locCur[da.w >> BSHIFT], 1);
        int t4 = atomicAdd(&locCur[db.x >> BSHIFT], 1);
        int t5 = atomicAdd(&locCur[db.y >> BSHIFT], 1);
        int t6 = atomicAdd(&locCur[db.z >> BSHIFT], 1);
        int t7 = atomicAdd(&locCur[db.w >> BSHIFT], 1);
        pack[t0] = (ea.x << (SRC_BITS + 8)) | ((da.x & (BNODES - 1)) << SRC_BITS) | sa.x;
        pack[t1] = (ea.y << (SRC_BITS + 8)) | ((da.y & (BNODES - 1)) << SRC_BITS) | sa.y;
        pack[t2] = (ea.z << (SRC_BITS + 8)) | ((da.z & (BNODES - 1)) << SRC_BITS) | sa.z;
        pack[t3] = (ea.w << (SRC_BITS + 8)) | ((da.w & (BNODES - 1)) << SRC_BITS) | sa.w;
        pack[t4] = (eb.x << (SRC_BITS + 8)) | ((db.x & (BNODES - 1)) << SRC_BITS) | sb.x;
        pack[t5] = (eb.y << (SRC_BITS + 8)) | ((db.y & (BNODES - 1)) << SRC_BITS) | sb.y;
        pack[t6] = (eb.z << (SRC_BITS + 8)) | ((db.z & (BNODES - 1)) << SRC_BITS) | sb.z;
        pack[t7] = (eb.w << (SRC_BITS + 8)) | ((db.w & (BNODES - 1)) << SRC_BITS) | sb.w;
    } else {                                   // tail chunk: scalar
        for (int j = start + threadIdx.x; j < end; j += PB)
            atomicAdd(&hist[dst[j] >> BSHIFT], 1);
        __syncthreads();
        for (int i = threadIdx.x; i < nbk; i += PB) {
            int h = hist[i];
            locCur[i] = h ? i * cap + atomicAdd(&cursor[i], h) : 0;
        }
        __syncthreads();
        for (int j = start + threadIdx.x; j < end; j += PB) {
            int d = dst[j];
            int slot = atomicAdd(&locCur[d >> BSHIFT], 1);
            pack[slot] = (etype[j] << (SRC_BITS + 8)) | ((d & (BNODES - 1)) << SRC_BITS) | src[j];
        }
    }
}

// ---- sort bucket by dstLow: ONE int4 global read into LDS (hist fused), LDS->LDS
// rank-scatter (2-wide), int4 write-back, per-node offsets, base[] segmented sums. ----
__global__ void sort_base_kernel(int* __restrict__ pack, const int* __restrict__ cursor,
                                 const int* __restrict__ ntype, const float* __restrict__ table,
                                 float* __restrict__ base, int* __restrict__ nodeOffG,
                                 int N, int cap) {
    __shared__ int rawL[CAPC];
    __shared__ int sortedL[CAPC];
    __shared__ float tbl[TABLE_SIZE];
    __shared__ int nodeCnt[BNODES];
    __shared__ int nodeOff[BNODES + 1];
    __shared__ unsigned char ntLoc[BNODES];
    int b = blockIdx.x;
    int node0 = b << BSHIFT;
    int tid = threadIdx.x;
    int st = b * cap;                 // cap is 256-aligned -> st*4 bytes is 16B-aligned
    int c = min(cursor[b], cap);

    if (tid < TABLE_SIZE) tbl[tid] = table[tid];
    if (tid < BNODES) {
        nodeCnt[tid] = 0;
        int n = node0 + tid;
        ntLoc[tid] = (n < N) ? (unsigned char)ntype[n] : 0;
    }
    __syncthreads();

    // pass 1: int4 load into rawL + histogram by dstLow (single global read)
    int c4 = c & ~3;
    for (int j = tid * 4; j < c4; j += HB * 4) {
        int4 v = *(const int4*)(pack + st + j);
        *(int4*)(rawL + j) = v;
        atomicAdd(&nodeCnt[(v.x >> SRC_BITS) & (BNODES - 1)], 1);
        atomicAdd(&nodeCnt[(v.y >> SRC_BITS) & (BNODES - 1)], 1);
        atomicAdd(&nodeCnt[(v.z >> SRC_BITS) & (BNODES - 1)], 1);
        atomicAdd(&nodeCnt[(v.w >> SRC_BITS) & (BNODES - 1)], 1);
    }
    for (int j = c4 + tid; j < c; j += HB) {
        int p = pack[st + j];
        rawL[j] = p;
        atomicAdd(&nodeCnt[(p >> SRC_BITS) & (BNODES - 1)], 1);
    }
    __syncthreads();

    // exclusive scan of 256 counts on wave 0
    if (tid < 64) {
        int lane = tid;
        int v0 = nodeCnt[lane * 4], v1 = nodeCnt[lane * 4 + 1];
        int v2 = nodeCnt[lane * 4 + 2], v3 = nodeCnt[lane * 4 + 3];
        int s = v0 + v1 + v2 + v3;
        int inc = s;
        for (int d = 1; d < 64; d <<= 1) {
            int t = __shfl_up(inc, d, 64);
            if (lane >= d) inc += t;
        }
        int excl = inc - s;
        nodeOff[lane * 4]     = excl;
        nodeOff[lane * 4 + 1] = excl + v0;
        nodeOff[lane * 4 + 2] = excl + v0 + v1;
        nodeOff[lane * 4 + 3] = excl + v0 + v1 + v2;
        if (lane == 63) nodeOff[BNODES] = inc;
    }
    __syncthreads();
    if (tid < BNODES) nodeCnt[tid] = 0;  // reuse as rank cursor
    __syncthreads();

    // pass 2: rank + scatter LDS -> LDS, two independent chains per iteration
    {
        int j = tid;
        for (; j + HB < c; j += 2 * HB) {
            int p0 = rawL[j];
            int p1 = rawL[j + HB];
            int dl0 = (p0 >> SRC_BITS) & (BNODES - 1);
            int dl1 = (p1 >> SRC_BITS) & (BNODES - 1);
            int r0 = atomicAdd(&nodeCnt[dl0], 1);
            int r1 = atomicAdd(&nodeCnt[dl1], 1);
            sortedL[nodeOff[dl0] + r0] = p0;
            sortedL[nodeOff[dl1] + r1] = p1;
        }
        if (j < c) {
            int p = rawL[j];
            int dl = (p >> SRC_BITS) & (BNODES - 1);
            int r = atomicAdd(&nodeCnt[dl], 1);
            sortedL[nodeOff[dl] + r] = p;
        }
    }
    __syncthreads();

    // int4 write-back of sorted slice + per-node offsets
    for (int j = tid * 4; j < c4; j += HB * 4)
        *(int4*)(pack + st + j) = *(const int4*)(sortedL + j);
    for (int j = c4 + tid; j < c; j += HB) pack[st + j] = sortedL[j];
    if (tid < BNODES) nodeOffG[(b << BSHIFT) + tid] = nodeOff[tid];

    // base: 4 lanes/node segmented sum of table values
    int node = tid >> 2, l = tid & 3;
    int lo = nodeOff[node], hi = nodeOff[node + 1];
    int nt = ntLoc[node];
    float s = 0.0f;
    int j = lo + l;
    for (; j + 4 < hi; j += 8) {
        int p0 = sortedL[j], p1 = sortedL[j + 4];
        s += tbl[((((unsigned)p0) >> (SRC_BITS + 8)) << 4) | (ntype[p0 & SRC_MASK] << 2) | nt]
           + tbl[((((unsigned)p1) >> (SRC_BITS + 8)) << 4) | (ntype[p1 & SRC_MASK] << 2) | nt];
    }
    if (j < hi) {
        int p = sortedL[j];
        s += tbl[((((unsigned)p) >> (SRC_BITS + 8)) << 4) | (ntype[p & SRC_MASK] << 2) | nt];
    }
    s += __shfl_xor(s, 1, 64);
    s += __shfl_xor(s, 2, 64);
    int n = node0 + node;
    if (l == 0 && n < N) base[n] = s;
}

// ---- hops 2-4: CSR segmented sums, 2 blocks per bucket (128 nodes each),
// 4 lanes/node, 4-wide gather unroll. Atomic-free. ----
__global__ __launch_bounds__(512)
void hop_csr_kernel(const int* __restrict__ pack, const int* __restrict__ nodeOffG,
                    const int* __restrict__ cursor, const float* __restrict__ base,
                    const float* __restrict__ prev, float* __restrict__ out,
                    int N, int cap) {
    __shared__ int off[129];
    int blk = blockIdx.x;
    int b = blk >> 1;
    int half = blk & 1;
    int tid = threadIdx.x;
    int st = b * cap;
    int nodeBase = (b << BSHIFT) + half * 128;
    if (tid < 128) off[tid] = nodeOffG[(b << BSHIFT) + half * 128 + tid];
    else if (tid == 128)
        off[128] = half ? min(cursor[b], cap) : nodeOffG[(b << BSHIFT) + 128];
    __syncthreads();
    int node = tid >> 2, l = tid & 3;   // node in 0..127
    int lo = off[node], hi = off[node + 1];
    float s = 0.0f;
    int j = st + lo + l;
    int hiG = st + hi;
    for (; j + 12 < hiG; j += 16) {
        int p0 = pack[j], p1 = pack[j + 4], p2 = pack[j + 8], p3 = pack[j + 12];
        s += prev[p0 & SRC_MASK] + prev[p1 & SRC_MASK]
           + prev[p2 & SRC_MASK] + prev[p3 & SRC_MASK];
    }
    for (; j < hiG; j += 4) s += prev[pack[j] & SRC_MASK];
    s += __shfl_xor(s, 1, 64);
    s += __shfl_xor(s, 2, 64);
    int n = nodeBase + node;
    if (l == 0 && n < N) out[n] = base[n] + s;
}

// ================= edge-parallel atomic fallback (tiny ws) =================
__global__ void edge_base_kernel(const int* __restrict__ src, const int* __restrict__ dst,
                                 const int* __restrict__ etype, const int* __restrict__ ntype,
                                 const float* __restrict__ table, float* __restrict__ base, int E) {
    __shared__ float tbl[TABLE_SIZE];
    for (int i = threadIdx.x; i < TABLE_SIZE; i += blockDim.x) tbl[i] = table[i];
    __syncthreads();
    int e = blockIdx.x * blockDim.x + threadIdx.x;
    if (e >= E) return;
    int s = src[e];
    int d = dst[e];
    int idx = (etype[e] << 4) | (ntype[s] << 2) | ntype[d];
    atomicAdd(base + d, tbl[idx]);
}

__global__ void copy_kernel(const float* __restrict__ in, float* __restrict__ out, int N) {
    int i = blockIdx.x * blockDim.x + threadIdx.x;
    if (i < N) out[i] = in[i];
}

__global__ void edge_hop_kernel(const int* __restrict__ src, const int* __restrict__ dst,
                                const float* __restrict__ prev, float* __restrict__ next, int E) {
    int e = blockIdx.x * blockDim.x + threadIdx.x;
    if (e >= E) return;
    atomicAdd(next + dst[e], prev[src[e]]);
}

extern "C" void kernel_launch(void* const* d_in, const int* in_sizes, int n_in,
                              void* d_out, int out_size, void* d_ws, size_t ws_size,
                              hipStream_t stream) {
    const int* edge_index = (const int*)d_in[0];   // (2, E)
    const int* etype      = (const int*)d_in[1];   // (E,)
    const int* ntype      = (const int*)d_in[2];   // (N,)
    const float* W1       = (const float*)d_in[3];
    const float* b1       = (const float*)d_in[4];
    const float* W2       = (const float*)d_in[5];
    const float* b2       = (const float*)d_in[6];

    const int E = in_sizes[1];
    const int N = in_sizes[2];
    const int* src = edge_index;
    const int* dst = edge_index + E;
    float* out = (float*)d_out;

    const int nbk = (N + BNODES - 1) >> BSHIFT;      // 391 for N=100000
    const int nChunks = (E + CHUNK - 1) / CHUNK;     // 391 for E=1.6M

    int cap = ((E / (nbk > 0 ? nbk : 1)) * 3 / 2 + 255) & ~255;  // 1.5x mean, 256-aligned
    if (cap < 512) cap = 512;
    size_t packElems = (size_t)nbk * cap;

    // ws layout (4B units): pack[nbk*cap] | cursor[MAXB] | nodeOffG[nbk*256]
    //                       | table[1024] | base[N] | bufA[N] | bufB[N]
    size_t need = (packElems + MAXB + (size_t)nbk * BNODES + 1024 + (size_t)3 * N) * 4 + 256;

    if (ws_size >= need && nbk <= MAXB && cap <= CAPC) {
        int* pack     = (int*)d_ws;
        int* cursor   = pack + packElems;
        int* nodeOffG = cursor + MAXB;
        float* table  = (float*)(nodeOffG + (size_t)nbk * BNODES);
        float* base   = table + 1024;
        float* bufA   = base + N;
        float* bufB   = bufA + N;

        init_kernel<<<1, 1024, 0, stream>>>(W1, b1, W2, b2, table, cursor);
        partition_kernel<<<nChunks, PB, 0, stream>>>(src, dst, etype, cursor, pack, E, nbk, cap);
        sort_base_kernel<<<nbk, HB, 0, stream>>>(pack, cursor, ntype, table, base, nodeOffG, N, cap);
        hop_csr_kernel<<<2 * nbk, 512, 0, stream>>>(pack, nodeOffG, cursor, base, base, bufA, N, cap);
        hop_csr_kernel<<<2 * nbk, 512, 0, stream>>>(pack, nodeOffG, cursor, base, bufA, bufB, N, cap);
        hop_csr_kernel<<<2 * nbk, 512, 0, stream>>>(pack, nodeOffG, cursor, base, bufB, out, N, cap);
    } else {
        // fallback: edge-parallel atomic path
        float* table = (float*)d_ws;
        float* base  = table + 1024;
        float* bufA  = base + N;
        float* bufB  = bufA + N;
        const int eb = (E + 255) / 256;
        const int nb = (N + 255) / 256;

        hipMemsetAsync(base, 0, (size_t)N * sizeof(float), stream);
        table_kernel<<<(TABLE_SIZE + 255) / 256, 256, 0, stream>>>(W1, b1, W2, b2, table);

        edge_base_kernel<<<eb, 256, 0, stream>>>(src, dst, etype, ntype, table, base, E);
        copy_kernel<<<nb, 256, 0, stream>>>(base, bufA, N);
        edge_hop_kernel<<<eb, 256, 0, stream>>>(src, dst, base, bufA, E);
        copy_kernel<<<nb, 256, 0, stream>>>(base, bufB, N);
        edge_hop_kernel<<<eb, 256, 0, stream>>>(src, dst, bufA, bufB, E);
        copy_kernel<<<nb, 256, 0, stream>>>(base, out, N);
        edge_hop_kernel<<<eb, 256, 0, stream>>>(src, dst, bufB, out, E);
    }
}